// Round 5
// baseline (1415.669 us; speedup 1.0000x reference)
//
#include <hip/hip_runtime.h>

typedef unsigned int uint32;

// ---------------------------------------------------------------- utilities

__device__ __forceinline__ int rl(int v, int l) {
    return __builtin_amdgcn_readlane(v, l);
}
__device__ __forceinline__ float rlf(int v, int l) {
    return __int_as_float(__builtin_amdgcn_readlane(v, l));
}
__device__ __forceinline__ uint32 f2bf(float x) {  // RNE f32 -> bf16 (low 16 bits)
    uint32 u = __float_as_uint(x);
    return (u + 0x7fffu + ((u >> 16) & 1u)) >> 16;
}
__device__ __forceinline__ float bfLo(uint32 u) { return __uint_as_float(u << 16); }
__device__ __forceinline__ float bfHi(uint32 u) { return __uint_as_float(u & 0xffff0000u); }

__global__ void count_kernel(const int* __restrict__ dst, int* __restrict__ cnt, int E) {
    int i = blockIdx.x * blockDim.x + threadIdx.x;
    if (i < E) atomicAdd(&cnt[dst[i]], 1);
}

// single-block exclusive scan of cnt -> roff; also emits dinv = rsqrt(cnt+1)
__global__ __launch_bounds__(1024) void scan_kernel(const int* __restrict__ cnt,
                                                    int* __restrict__ roff,
                                                    float* __restrict__ dinv, int n) {
    __shared__ int wsum[16];
    __shared__ int carry_s, total_s;
    int tid = threadIdx.x;
    int lane = tid & 63, w = tid >> 6;
    if (tid == 0) carry_s = 0;
    __syncthreads();
    for (int base = 0; base < n; base += 1024) {
        int i = base + tid;
        int v = (i < n) ? cnt[i] : 0;
        if (i < n) dinv[i] = rsqrtf((float)v + 1.0f);  // +1 self-loop
        int s = v;
#pragma unroll
        for (int d = 1; d < 64; d <<= 1) {
            int t = __shfl_up(s, d, 64);
            if (lane >= d) s += t;
        }
        if (lane == 63) wsum[w] = s;
        __syncthreads();
        if (w == 0) {
            int wv = (lane < 16) ? wsum[lane] : 0;
            int ss = wv;
#pragma unroll
            for (int d = 1; d < 16; d <<= 1) {
                int t = __shfl_up(ss, d, 64);
                if (lane >= d) ss += t;
            }
            if (lane < 16) wsum[lane] = ss - wv;   // exclusive wave offsets
            if (lane == 15) total_s = ss;          // chunk total
        }
        __syncthreads();
        int carry = carry_s;
        if (i < n) roff[i] = carry + wsum[w] + (s - v);
        __syncthreads();
        if (tid == 0) carry_s += total_s;
        __syncthreads();
    }
}

// emits interleaved (src, norm) pairs per edge slot
__global__ void scatter_kernel(const int* __restrict__ src, const int* __restrict__ dst,
                               const int* __restrict__ roff, int* __restrict__ cur,
                               const float* __restrict__ dinv,
                               int2* __restrict__ ese, int E) {
    int i = blockIdx.x * blockDim.x + threadIdx.x;
    if (i < E) {
        int d = dst[i], s = src[i];
        int p = roff[d] + atomicAdd(&cur[d], 1);
        ese[p] = make_int2(s, __float_as_int(dinv[s] * dinv[d]));
    }
}

// ---------------------------------------------------------------- fp32 GEMM
// C[M x 256] = A[M x K] * B[K x 256], row-major. Tile 128x128xBK8, 256 thr, 8x8/thr.
// Needs ~110-128 live VGPRs in the K-loop (64 acc + 16 a/b + addressing).
// __launch_bounds__(256, 4) pins the VGPR budget at 128: without it the
// compiler chose 92 VGPRs -> scratch spills in the K-loop -> 59 TF (R4 was
// 223 us vs R2's 84.5 us @ 128 VGPR, 154 TF = 98% of fp32 vector roofline).
// OUT_MODE: 1 = fp32 bias+relu, 2 = raw bf16 (packed 2/uint)
template <int K, int OUT_MODE>
__device__ __forceinline__ void sgemm_body(const float* __restrict__ A,
                                           const float* __restrict__ B,
                                           const float* __restrict__ bias,
                                           float* __restrict__ C, int M) {
    __shared__ float As[8][128];
    __shared__ float Bs[8][128];
    int tid = threadIdx.x;
    int tx = tid & 15, ty = tid >> 4;
    int rowBase = blockIdx.x * 128;
    int colBase = blockIdx.y * 128;
    float acc[8][8] = {};
    int ar = rowBase + (tid >> 1);
    int ak = (tid & 1) * 4;
    int bk = tid >> 5;
    int bn = colBase + (tid & 31) * 4;

    for (int k0 = 0; k0 < K; k0 += 8) {
        float4 av = make_float4(0.f, 0.f, 0.f, 0.f);
        if (ar < M) av = *(const float4*)&A[(size_t)ar * K + k0 + ak];
        float4 bv = *(const float4*)&B[(size_t)(k0 + bk) * 256 + bn];
        __syncthreads();
        As[ak + 0][tid >> 1] = av.x;
        As[ak + 1][tid >> 1] = av.y;
        As[ak + 2][tid >> 1] = av.z;
        As[ak + 3][tid >> 1] = av.w;
        *(float4*)&Bs[bk][(tid & 31) * 4] = bv;
        __syncthreads();
#pragma unroll
        for (int kk = 0; kk < 8; ++kk) {
            float4 a0 = *(const float4*)&As[kk][ty * 8];
            float4 a1 = *(const float4*)&As[kk][ty * 8 + 4];
            float4 b0 = *(const float4*)&Bs[kk][tx * 8];
            float4 b1 = *(const float4*)&Bs[kk][tx * 8 + 4];
            float a[8] = {a0.x, a0.y, a0.z, a0.w, a1.x, a1.y, a1.z, a1.w};
            float b[8] = {b0.x, b0.y, b0.z, b0.w, b1.x, b1.y, b1.z, b1.w};
#pragma unroll
            for (int i = 0; i < 8; ++i)
#pragma unroll
                for (int j = 0; j < 8; ++j) acc[i][j] += a[i] * b[j];
        }
    }
    float bcol[8];
#pragma unroll
    for (int j = 0; j < 8; ++j) bcol[j] = (OUT_MODE == 1) ? bias[colBase + tx * 8 + j] : 0.f;
#pragma unroll
    for (int i = 0; i < 8; ++i) {
        int r = rowBase + ty * 8 + i;
        if (r < M) {
            if (OUT_MODE == 2) {
                uint32* Cb = (uint32*)C;  // bf16 pairs, row stride 128 uints
                uint4 pk;
                pk.x = f2bf(acc[i][0]) | (f2bf(acc[i][1]) << 16);
                pk.y = f2bf(acc[i][2]) | (f2bf(acc[i][3]) << 16);
                pk.z = f2bf(acc[i][4]) | (f2bf(acc[i][5]) << 16);
                pk.w = f2bf(acc[i][6]) | (f2bf(acc[i][7]) << 16);
                *(uint4*)&Cb[(size_t)r * 128 + (colBase >> 1) + tx * 4] = pk;
            } else {
                float o[8];
#pragma unroll
                for (int j = 0; j < 8; ++j)
                    o[j] = fmaxf(acc[i][j] + bcol[j], 0.f);
                *(float4*)&C[(size_t)r * 256 + colBase + tx * 8] =
                    make_float4(o[0], o[1], o[2], o[3]);
                *(float4*)&C[(size_t)r * 256 + colBase + tx * 8 + 4] =
                    make_float4(o[4], o[5], o[6], o[7]);
            }
        }
    }
}

__global__ __launch_bounds__(256, 4) void sgemm1_kernel(const float* __restrict__ A,
                                                        const float* __restrict__ B,
                                                        const float* __restrict__ bias,
                                                        float* __restrict__ C, int M) {
    sgemm_body<128, 1>(A, B, bias, C, M);
}

__global__ __launch_bounds__(256, 4) void sgemm2_kernel(const float* __restrict__ A,
                                                        const float* __restrict__ B,
                                                        float* __restrict__ C, int M) {
    sgemm_body<256, 2>(A, B, nullptr, C, M);
}

// ------------------------------------------------------------- aggregation
// Layer 1: one wave per node, fp32 float2/lane over D=128 rows of x.
// Edge (src,norm) batches (64 int2) vector-loaded then readlane-broadcast;
// row gathers unrolled x8 for 8 loads in flight.
__global__ __launch_bounds__(256) void agg1_kernel(const float2* __restrict__ X,
                                                   const int* __restrict__ roff,
                                                   const int* __restrict__ cnt,
                                                   const int2* __restrict__ ese,
                                                   const float* __restrict__ dinv,
                                                   float2* __restrict__ out, int n) {
    int wv = threadIdx.x >> 6, lane = threadIdx.x & 63;
    int node = blockIdx.x * 4 + wv;
    if (node >= n) return;

    float di = dinv[node];
    float sn = di * di;  // self-loop norm
    float2 acc = X[(size_t)node * 64 + lane];
    acc.x *= sn; acc.y *= sn;

    int beg = roff[node], m = cnt[node];
    for (int base = 0; base < m; base += 64) {
        int mm = min(64, m - base);
        int2 ev = make_int2(0, 0);
        if (lane < mm) ev = ese[beg + base + lane];
        int e = 0;
        for (; e + 8 <= mm; e += 8) {
            int s0 = rl(ev.x, e + 0), s1 = rl(ev.x, e + 1);
            int s2 = rl(ev.x, e + 2), s3 = rl(ev.x, e + 3);
            int s4 = rl(ev.x, e + 4), s5 = rl(ev.x, e + 5);
            int s6 = rl(ev.x, e + 6), s7 = rl(ev.x, e + 7);
            float n0 = rlf(ev.y, e + 0), n1 = rlf(ev.y, e + 1);
            float n2 = rlf(ev.y, e + 2), n3 = rlf(ev.y, e + 3);
            float n4 = rlf(ev.y, e + 4), n5 = rlf(ev.y, e + 5);
            float n6 = rlf(ev.y, e + 6), n7 = rlf(ev.y, e + 7);
            float2 h0 = X[(size_t)s0 * 64 + lane];
            float2 h1 = X[(size_t)s1 * 64 + lane];
            float2 h2 = X[(size_t)s2 * 64 + lane];
            float2 h3 = X[(size_t)s3 * 64 + lane];
            float2 h4 = X[(size_t)s4 * 64 + lane];
            float2 h5 = X[(size_t)s5 * 64 + lane];
            float2 h6 = X[(size_t)s6 * 64 + lane];
            float2 h7 = X[(size_t)s7 * 64 + lane];
            acc.x += h0.x * n0 + h1.x * n1 + h2.x * n2 + h3.x * n3;
            acc.y += h0.y * n0 + h1.y * n1 + h2.y * n2 + h3.y * n3;
            acc.x += h4.x * n4 + h5.x * n5 + h6.x * n6 + h7.x * n7;
            acc.y += h4.y * n4 + h5.y * n5 + h6.y * n6 + h7.y * n7;
        }
        for (; e < mm; ++e) {
            int s0 = rl(ev.x, e);
            float n0 = rlf(ev.y, e);
            float2 h0 = X[(size_t)s0 * 64 + lane];
            acc.x += h0.x * n0;
            acc.y += h0.y * n0;
        }
    }
    out[(size_t)node * 64 + lane] = acc;
}

// Layer 2: 2 waves per node, bf16 payload (1 uint = 2 channels per lane),
// fp32 accumulate, fused bias + relu, fp32 output.
__global__ __launch_bounds__(256) void agg2_kernel(const uint32* __restrict__ Hbf,
                                                   const int* __restrict__ roff,
                                                   const int* __restrict__ cnt,
                                                   const int2* __restrict__ ese,
                                                   const float* __restrict__ dinv,
                                                   const float* __restrict__ bias,
                                                   float2* __restrict__ out, int n) {
    int wv = threadIdx.x >> 6, lane = threadIdx.x & 63;
    int gw = blockIdx.x * 4 + wv;
    int node = gw >> 1, half = gw & 1;
    if (node >= n) return;
    int offU = half * 64 + lane;  // uint offset within row (128 uints/row)

    float di = dinv[node];
    float sn = di * di;
    uint32 sg = Hbf[(size_t)node * 128 + offU];
    float2 acc;
    acc.x = bfLo(sg) * sn;
    acc.y = bfHi(sg) * sn;

    int beg = roff[node], m = cnt[node];
    for (int base = 0; base < m; base += 64) {
        int mm = min(64, m - base);
        int2 ev = make_int2(0, 0);
        if (lane < mm) ev = ese[beg + base + lane];
        int e = 0;
        for (; e + 8 <= mm; e += 8) {
            int s0 = rl(ev.x, e + 0), s1 = rl(ev.x, e + 1);
            int s2 = rl(ev.x, e + 2), s3 = rl(ev.x, e + 3);
            int s4 = rl(ev.x, e + 4), s5 = rl(ev.x, e + 5);
            int s6 = rl(ev.x, e + 6), s7 = rl(ev.x, e + 7);
            float n0 = rlf(ev.y, e + 0), n1 = rlf(ev.y, e + 1);
            float n2 = rlf(ev.y, e + 2), n3 = rlf(ev.y, e + 3);
            float n4 = rlf(ev.y, e + 4), n5 = rlf(ev.y, e + 5);
            float n6 = rlf(ev.y, e + 6), n7 = rlf(ev.y, e + 7);
            uint32 g0 = Hbf[(size_t)s0 * 128 + offU];
            uint32 g1 = Hbf[(size_t)s1 * 128 + offU];
            uint32 g2 = Hbf[(size_t)s2 * 128 + offU];
            uint32 g3 = Hbf[(size_t)s3 * 128 + offU];
            uint32 g4 = Hbf[(size_t)s4 * 128 + offU];
            uint32 g5 = Hbf[(size_t)s5 * 128 + offU];
            uint32 g6 = Hbf[(size_t)s6 * 128 + offU];
            uint32 g7 = Hbf[(size_t)s7 * 128 + offU];
            acc.x += bfLo(g0) * n0 + bfLo(g1) * n1 + bfLo(g2) * n2 + bfLo(g3) * n3;
            acc.y += bfHi(g0) * n0 + bfHi(g1) * n1 + bfHi(g2) * n2 + bfHi(g3) * n3;
            acc.x += bfLo(g4) * n4 + bfLo(g5) * n5 + bfLo(g6) * n6 + bfLo(g7) * n7;
            acc.y += bfHi(g4) * n4 + bfHi(g5) * n5 + bfHi(g6) * n6 + bfHi(g7) * n7;
        }
        for (; e < mm; ++e) {
            int s0 = rl(ev.x, e);
            float n0 = rlf(ev.y, e);
            uint32 g0 = Hbf[(size_t)s0 * 128 + offU];
            acc.x += bfLo(g0) * n0;
            acc.y += bfHi(g0) * n0;
        }
    }
    float2 bb = ((const float2*)bias)[offU];
    acc.x = fmaxf(acc.x + bb.x, 0.f);
    acc.y = fmaxf(acc.y + bb.y, 0.f);
    out[(size_t)node * 128 + offU] = acc;
}

// ---------------------------------------------------------------- launcher

extern "C" void kernel_launch(void* const* d_in, const int* in_sizes, int n_in,
                              void* d_out, int out_size, void* d_ws, size_t ws_size,
                              hipStream_t stream) {
    const float* x  = (const float*)d_in[0];
    const int*   ei = (const int*)d_in[1];
    const float* W1 = (const float*)d_in[2];
    const float* b1 = (const float*)d_in[3];
    const float* W2 = (const float*)d_in[4];
    const float* b2 = (const float*)d_in[5];
    float* out = (float*)d_out;

    const int n = in_sizes[0] / 128;   // 100000 nodes
    const int E = in_sizes[1] / 2;     // 1.6M edges
    const int* src = ei;
    const int* dst = ei + E;

    // workspace carve-up (256B aligned); cnt+cur adjacent -> one memset
    size_t off = 0;
    auto alloc = [&](size_t bytes) {
        void* p = (char*)d_ws + off;
        off += (bytes + 255) & ~(size_t)255;
        return p;
    };
    int*   cnt  = (int*)alloc((size_t)n * 4);
    int*   cur  = (int*)alloc((size_t)n * 4);
    int*   roff = (int*)alloc((size_t)n * 4);
    float* dinv = (float*)alloc((size_t)n * 4);
    int2*  ese  = (int2*)alloc((size_t)E * 8);
    // shared buffer: agg1 output (n x 128 fp32 = 51.2MB), then h2-bf16 (n x 256 bf16 = 51.2MB)
    float* buf  = (float*)alloc((size_t)n * 128 * 4);
    (void)ws_size;

    // ---- graph build
    hipMemsetAsync(cnt, 0, (size_t)(2 * n + 128) * 4, stream);  // cnt + cur (adjacent)
    count_kernel<<<(E + 255) / 256, 256, 0, stream>>>(dst, cnt, E);
    scan_kernel<<<1, 1024, 0, stream>>>(cnt, roff, dinv, n);
    scatter_kernel<<<(E + 255) / 256, 256, 0, stream>>>(src, dst, roff, cur, dinv, ese, E);

    dim3 g1((n + 127) / 128, 2);
    // ---- layer 1: ax = Âx (128-dim); out = relu(ax @ W1 + b1)
    agg1_kernel<<<(n + 3) / 4, 256, 0, stream>>>(
        (const float2*)x, roff, cnt, ese, dinv, (float2*)buf, n);
    sgemm1_kernel<<<g1, 256, 0, stream>>>(buf, W1, b1, out, n);

    // ---- layer 2: h2 = bf16(out @ W2) ; out = relu(Â h2 + b2)
    sgemm2_kernel<<<g1, 256, 0, stream>>>(out, W2, buf, n);
    agg2_kernel<<<(2 * n + 3) / 4, 256, 0, stream>>>(
        (const uint32*)buf, roff, cnt, ese, dinv, b2, (float2*)out, n);
}

// Round 6
// 939.473 us; speedup vs baseline: 1.5069x; 1.5069x over previous
//
#include <hip/hip_runtime.h>

typedef unsigned int uint32;

// ---------------------------------------------------------------- utilities

__device__ __forceinline__ int rl(int v, int l) {
    return __builtin_amdgcn_readlane(v, l);
}
__device__ __forceinline__ float rlf(int v, int l) {
    return __int_as_float(__builtin_amdgcn_readlane(v, l));
}
__device__ __forceinline__ uint32 f2bf(float x) {  // RNE f32 -> bf16 (low 16 bits)
    uint32 u = __float_as_uint(x);
    return (u + 0x7fffu + ((u >> 16) & 1u)) >> 16;
}
__device__ __forceinline__ float bfLo(uint32 u) { return __uint_as_float(u << 16); }
__device__ __forceinline__ float bfHi(uint32 u) { return __uint_as_float(u & 0xffff0000u); }

__global__ void count_kernel(const int* __restrict__ dst, int* __restrict__ cnt, int E) {
    int i = blockIdx.x * blockDim.x + threadIdx.x;
    if (i < E) atomicAdd(&cnt[dst[i]], 1);
}

// single-block exclusive scan of cnt -> roff; also emits dinv = rsqrt(cnt+1)
__global__ __launch_bounds__(1024) void scan_kernel(const int* __restrict__ cnt,
                                                    int* __restrict__ roff,
                                                    float* __restrict__ dinv, int n) {
    __shared__ int wsum[16];
    __shared__ int carry_s, total_s;
    int tid = threadIdx.x;
    int lane = tid & 63, w = tid >> 6;
    if (tid == 0) carry_s = 0;
    __syncthreads();
    for (int base = 0; base < n; base += 1024) {
        int i = base + tid;
        int v = (i < n) ? cnt[i] : 0;
        if (i < n) dinv[i] = rsqrtf((float)v + 1.0f);  // +1 self-loop
        int s = v;
#pragma unroll
        for (int d = 1; d < 64; d <<= 1) {
            int t = __shfl_up(s, d, 64);
            if (lane >= d) s += t;
        }
        if (lane == 63) wsum[w] = s;
        __syncthreads();
        if (w == 0) {
            int wv = (lane < 16) ? wsum[lane] : 0;
            int ss = wv;
#pragma unroll
            for (int d = 1; d < 16; d <<= 1) {
                int t = __shfl_up(ss, d, 64);
                if (lane >= d) ss += t;
            }
            if (lane < 16) wsum[lane] = ss - wv;   // exclusive wave offsets
            if (lane == 15) total_s = ss;          // chunk total
        }
        __syncthreads();
        int carry = carry_s;
        if (i < n) roff[i] = carry + wsum[w] + (s - v);
        __syncthreads();
        if (tid == 0) carry_s += total_s;
        __syncthreads();
    }
}

// emits interleaved (src, norm) pairs per edge slot
__global__ void scatter_kernel(const int* __restrict__ src, const int* __restrict__ dst,
                               const int* __restrict__ roff, int* __restrict__ cur,
                               const float* __restrict__ dinv,
                               int2* __restrict__ ese, int E) {
    int i = blockIdx.x * blockDim.x + threadIdx.x;
    if (i < E) {
        int d = dst[i], s = src[i];
        int p = roff[d] + atomicAdd(&cur[d], 1);
        ese[p] = make_int2(s, __float_as_int(dinv[s] * dinv[d]));
    }
}

// ---------------------------------------------------------------- fp32 GEMM
// C[M x 256] = A[M x K] * B[K x 256], row-major. Tile 128x128xBK8, 256 thr, 8x8/thr.
// K-loop needs ~130-160 live VGPRs (64 acc + 16 a/b + addressing + staged loads).
// VGPR-allocation history (rocprof VGPR_Count / WRITE_SIZE evidence):
//   no bound        -> 128 VGPR, no spill,   85 us  (R2: 154 TF = 98% fp32 roofline)
//   (256) template  ->  92 VGPR, mild spill, 223 us (R4)
//   (256,4) cap 128 ->  64 VGPR, 2GB scratch writes, 731 us (R5!)
// hipcc's heuristic chases occupancy ABOVE the declared min and spills; so
// declare min 2 waves/EU -> cap 512/2 = 256 VGPRs, giving headroom so the
// allocator has no incentive to spill.
// OUT_MODE: 1 = fp32 bias+relu, 2 = raw bf16 (packed 2/uint)
template <int K, int OUT_MODE>
__device__ __forceinline__ void sgemm_body(const float* __restrict__ A,
                                           const float* __restrict__ B,
                                           const float* __restrict__ bias,
                                           float* __restrict__ C, int M) {
    __shared__ float As[8][128];
    __shared__ float Bs[8][128];
    int tid = threadIdx.x;
    int tx = tid & 15, ty = tid >> 4;
    int rowBase = blockIdx.x * 128;
    int colBase = blockIdx.y * 128;
    float acc[8][8] = {};
    int ar = rowBase + (tid >> 1);
    int ak = (tid & 1) * 4;
    int bk = tid >> 5;
    int bn = colBase + (tid & 31) * 4;

    for (int k0 = 0; k0 < K; k0 += 8) {
        float4 av = make_float4(0.f, 0.f, 0.f, 0.f);
        if (ar < M) av = *(const float4*)&A[(size_t)ar * K + k0 + ak];
        float4 bv = *(const float4*)&B[(size_t)(k0 + bk) * 256 + bn];
        __syncthreads();
        As[ak + 0][tid >> 1] = av.x;
        As[ak + 1][tid >> 1] = av.y;
        As[ak + 2][tid >> 1] = av.z;
        As[ak + 3][tid >> 1] = av.w;
        *(float4*)&Bs[bk][(tid & 31) * 4] = bv;
        __syncthreads();
#pragma unroll
        for (int kk = 0; kk < 8; ++kk) {
            float4 a0 = *(const float4*)&As[kk][ty * 8];
            float4 a1 = *(const float4*)&As[kk][ty * 8 + 4];
            float4 b0 = *(const float4*)&Bs[kk][tx * 8];
            float4 b1 = *(const float4*)&Bs[kk][tx * 8 + 4];
            float a[8] = {a0.x, a0.y, a0.z, a0.w, a1.x, a1.y, a1.z, a1.w};
            float b[8] = {b0.x, b0.y, b0.z, b0.w, b1.x, b1.y, b1.z, b1.w};
#pragma unroll
            for (int i = 0; i < 8; ++i)
#pragma unroll
                for (int j = 0; j < 8; ++j) acc[i][j] += a[i] * b[j];
        }
    }
    float bcol[8];
#pragma unroll
    for (int j = 0; j < 8; ++j) bcol[j] = (OUT_MODE == 1) ? bias[colBase + tx * 8 + j] : 0.f;
#pragma unroll
    for (int i = 0; i < 8; ++i) {
        int r = rowBase + ty * 8 + i;
        if (r < M) {
            if (OUT_MODE == 2) {
                uint32* Cb = (uint32*)C;  // bf16 pairs, row stride 128 uints
                uint4 pk;
                pk.x = f2bf(acc[i][0]) | (f2bf(acc[i][1]) << 16);
                pk.y = f2bf(acc[i][2]) | (f2bf(acc[i][3]) << 16);
                pk.z = f2bf(acc[i][4]) | (f2bf(acc[i][5]) << 16);
                pk.w = f2bf(acc[i][6]) | (f2bf(acc[i][7]) << 16);
                *(uint4*)&Cb[(size_t)r * 128 + (colBase >> 1) + tx * 4] = pk;
            } else {
                float o[8];
#pragma unroll
                for (int j = 0; j < 8; ++j)
                    o[j] = fmaxf(acc[i][j] + bcol[j], 0.f);
                *(float4*)&C[(size_t)r * 256 + colBase + tx * 8] =
                    make_float4(o[0], o[1], o[2], o[3]);
                *(float4*)&C[(size_t)r * 256 + colBase + tx * 8 + 4] =
                    make_float4(o[4], o[5], o[6], o[7]);
            }
        }
    }
}

__global__ __launch_bounds__(256, 2) void sgemm1_kernel(const float* __restrict__ A,
                                                        const float* __restrict__ B,
                                                        const float* __restrict__ bias,
                                                        float* __restrict__ C, int M) {
    sgemm_body<128, 1>(A, B, bias, C, M);
}

__global__ __launch_bounds__(256, 2) void sgemm2_kernel(const float* __restrict__ A,
                                                        const float* __restrict__ B,
                                                        float* __restrict__ C, int M) {
    sgemm_body<256, 2>(A, B, nullptr, C, M);
}

// ------------------------------------------------------------- aggregation
// Layer 1: one wave per node, fp32 float2/lane over D=128 rows of x.
// Edge (src,norm) batches (64 int2) vector-loaded then readlane-broadcast;
// row gathers unrolled x8 for 8 loads in flight.
__global__ __launch_bounds__(256) void agg1_kernel(const float2* __restrict__ X,
                                                   const int* __restrict__ roff,
                                                   const int* __restrict__ cnt,
                                                   const int2* __restrict__ ese,
                                                   const float* __restrict__ dinv,
                                                   float2* __restrict__ out, int n) {
    int wv = threadIdx.x >> 6, lane = threadIdx.x & 63;
    int node = blockIdx.x * 4 + wv;
    if (node >= n) return;

    float di = dinv[node];
    float sn = di * di;  // self-loop norm
    float2 acc = X[(size_t)node * 64 + lane];
    acc.x *= sn; acc.y *= sn;

    int beg = roff[node], m = cnt[node];
    for (int base = 0; base < m; base += 64) {
        int mm = min(64, m - base);
        int2 ev = make_int2(0, 0);
        if (lane < mm) ev = ese[beg + base + lane];
        int e = 0;
        for (; e + 8 <= mm; e += 8) {
            int s0 = rl(ev.x, e + 0), s1 = rl(ev.x, e + 1);
            int s2 = rl(ev.x, e + 2), s3 = rl(ev.x, e + 3);
            int s4 = rl(ev.x, e + 4), s5 = rl(ev.x, e + 5);
            int s6 = rl(ev.x, e + 6), s7 = rl(ev.x, e + 7);
            float n0 = rlf(ev.y, e + 0), n1 = rlf(ev.y, e + 1);
            float n2 = rlf(ev.y, e + 2), n3 = rlf(ev.y, e + 3);
            float n4 = rlf(ev.y, e + 4), n5 = rlf(ev.y, e + 5);
            float n6 = rlf(ev.y, e + 6), n7 = rlf(ev.y, e + 7);
            float2 h0 = X[(size_t)s0 * 64 + lane];
            float2 h1 = X[(size_t)s1 * 64 + lane];
            float2 h2 = X[(size_t)s2 * 64 + lane];
            float2 h3 = X[(size_t)s3 * 64 + lane];
            float2 h4 = X[(size_t)s4 * 64 + lane];
            float2 h5 = X[(size_t)s5 * 64 + lane];
            float2 h6 = X[(size_t)s6 * 64 + lane];
            float2 h7 = X[(size_t)s7 * 64 + lane];
            acc.x += h0.x * n0 + h1.x * n1 + h2.x * n2 + h3.x * n3;
            acc.y += h0.y * n0 + h1.y * n1 + h2.y * n2 + h3.y * n3;
            acc.x += h4.x * n4 + h5.x * n5 + h6.x * n6 + h7.x * n7;
            acc.y += h4.y * n4 + h5.y * n5 + h6.y * n6 + h7.y * n7;
        }
        for (; e < mm; ++e) {
            int s0 = rl(ev.x, e);
            float n0 = rlf(ev.y, e);
            float2 h0 = X[(size_t)s0 * 64 + lane];
            acc.x += h0.x * n0;
            acc.y += h0.y * n0;
        }
    }
    out[(size_t)node * 64 + lane] = acc;
}

// Layer 2: 2 waves per node, bf16 payload (1 uint = 2 channels per lane),
// fp32 accumulate, fused bias + relu, fp32 output.
__global__ __launch_bounds__(256) void agg2_kernel(const uint32* __restrict__ Hbf,
                                                   const int* __restrict__ roff,
                                                   const int* __restrict__ cnt,
                                                   const int2* __restrict__ ese,
                                                   const float* __restrict__ dinv,
                                                   const float* __restrict__ bias,
                                                   float2* __restrict__ out, int n) {
    int wv = threadIdx.x >> 6, lane = threadIdx.x & 63;
    int gw = blockIdx.x * 4 + wv;
    int node = gw >> 1, half = gw & 1;
    if (node >= n) return;
    int offU = half * 64 + lane;  // uint offset within row (128 uints/row)

    float di = dinv[node];
    float sn = di * di;
    uint32 sg = Hbf[(size_t)node * 128 + offU];
    float2 acc;
    acc.x = bfLo(sg) * sn;
    acc.y = bfHi(sg) * sn;

    int beg = roff[node], m = cnt[node];
    for (int base = 0; base < m; base += 64) {
        int mm = min(64, m - base);
        int2 ev = make_int2(0, 0);
        if (lane < mm) ev = ese[beg + base + lane];
        int e = 0;
        for (; e + 8 <= mm; e += 8) {
            int s0 = rl(ev.x, e + 0), s1 = rl(ev.x, e + 1);
            int s2 = rl(ev.x, e + 2), s3 = rl(ev.x, e + 3);
            int s4 = rl(ev.x, e + 4), s5 = rl(ev.x, e + 5);
            int s6 = rl(ev.x, e + 6), s7 = rl(ev.x, e + 7);
            float n0 = rlf(ev.y, e + 0), n1 = rlf(ev.y, e + 1);
            float n2 = rlf(ev.y, e + 2), n3 = rlf(ev.y, e + 3);
            float n4 = rlf(ev.y, e + 4), n5 = rlf(ev.y, e + 5);
            float n6 = rlf(ev.y, e + 6), n7 = rlf(ev.y, e + 7);
            uint32 g0 = Hbf[(size_t)s0 * 128 + offU];
            uint32 g1 = Hbf[(size_t)s1 * 128 + offU];
            uint32 g2 = Hbf[(size_t)s2 * 128 + offU];
            uint32 g3 = Hbf[(size_t)s3 * 128 + offU];
            uint32 g4 = Hbf[(size_t)s4 * 128 + offU];
            uint32 g5 = Hbf[(size_t)s5 * 128 + offU];
            uint32 g6 = Hbf[(size_t)s6 * 128 + offU];
            uint32 g7 = Hbf[(size_t)s7 * 128 + offU];
            acc.x += bfLo(g0) * n0 + bfLo(g1) * n1 + bfLo(g2) * n2 + bfLo(g3) * n3;
            acc.y += bfHi(g0) * n0 + bfHi(g1) * n1 + bfHi(g2) * n2 + bfHi(g3) * n3;
            acc.x += bfLo(g4) * n4 + bfLo(g5) * n5 + bfLo(g6) * n6 + bfLo(g7) * n7;
            acc.y += bfHi(g4) * n4 + bfHi(g5) * n5 + bfHi(g6) * n6 + bfHi(g7) * n7;
        }
        for (; e < mm; ++e) {
            int s0 = rl(ev.x, e);
            float n0 = rlf(ev.y, e);
            uint32 g0 = Hbf[(size_t)s0 * 128 + offU];
            acc.x += bfLo(g0) * n0;
            acc.y += bfHi(g0) * n0;
        }
    }
    float2 bb = ((const float2*)bias)[offU];
    acc.x = fmaxf(acc.x + bb.x, 0.f);
    acc.y = fmaxf(acc.y + bb.y, 0.f);
    out[(size_t)node * 128 + offU] = acc;
}

// ---------------------------------------------------------------- launcher

extern "C" void kernel_launch(void* const* d_in, const int* in_sizes, int n_in,
                              void* d_out, int out_size, void* d_ws, size_t ws_size,
                              hipStream_t stream) {
    const float* x  = (const float*)d_in[0];
    const int*   ei = (const int*)d_in[1];
    const float* W1 = (const float*)d_in[2];
    const float* b1 = (const float*)d_in[3];
    const float* W2 = (const float*)d_in[4];
    const float* b2 = (const float*)d_in[5];
    float* out = (float*)d_out;

    const int n = in_sizes[0] / 128;   // 100000 nodes
    const int E = in_sizes[1] / 2;     // 1.6M edges
    const int* src = ei;
    const int* dst = ei + E;

    // workspace carve-up (256B aligned); cnt+cur adjacent -> one memset
    size_t off = 0;
    auto alloc = [&](size_t bytes) {
        void* p = (char*)d_ws + off;
        off += (bytes + 255) & ~(size_t)255;
        return p;
    };
    int*   cnt  = (int*)alloc((size_t)n * 4);
    int*   cur  = (int*)alloc((size_t)n * 4);
    int*   roff = (int*)alloc((size_t)n * 4);
    float* dinv = (float*)alloc((size_t)n * 4);
    int2*  ese  = (int2*)alloc((size_t)E * 8);
    // shared buffer: agg1 output (n x 128 fp32 = 51.2MB), then h2-bf16 (n x 256 bf16 = 51.2MB)
    float* buf  = (float*)alloc((size_t)n * 128 * 4);
    (void)ws_size;

    // ---- graph build
    hipMemsetAsync(cnt, 0, (size_t)(2 * n + 128) * 4, stream);  // cnt + cur (adjacent)
    count_kernel<<<(E + 255) / 256, 256, 0, stream>>>(dst, cnt, E);
    scan_kernel<<<1, 1024, 0, stream>>>(cnt, roff, dinv, n);
    scatter_kernel<<<(E + 255) / 256, 256, 0, stream>>>(src, dst, roff, cur, dinv, ese, E);

    dim3 g1((n + 127) / 128, 2);
    // ---- layer 1: ax = Âx (128-dim); out = relu(ax @ W1 + b1)
    agg1_kernel<<<(n + 3) / 4, 256, 0, stream>>>(
        (const float2*)x, roff, cnt, ese, dinv, (float2*)buf, n);
    sgemm1_kernel<<<g1, 256, 0, stream>>>(buf, W1, b1, out, n);

    // ---- layer 2: h2 = bf16(out @ W2) ; out = relu(Â h2 + b2)
    sgemm2_kernel<<<g1, 256, 0, stream>>>(out, W2, buf, n);
    agg2_kernel<<<(2 * n + 3) / 4, 256, 0, stream>>>(
        (const uint32*)buf, roff, cnt, ese, dinv, b2, (float2*)out, n);
}

// Round 7
// 933.593 us; speedup vs baseline: 1.5164x; 1.0063x over previous
//
#include <hip/hip_runtime.h>

typedef unsigned int uint32;

// ---------------------------------------------------------------- utilities

__device__ __forceinline__ int rl(int v, int l) {
    return __builtin_amdgcn_readlane(v, l);
}
__device__ __forceinline__ float rlf(int v, int l) {
    return __int_as_float(__builtin_amdgcn_readlane(v, l));
}
__device__ __forceinline__ uint32 f2bf(float x) {  // RNE f32 -> bf16 (low 16 bits)
    uint32 u = __float_as_uint(x);
    return (u + 0x7fffu + ((u >> 16) & 1u)) >> 16;
}
__device__ __forceinline__ float bfLo(uint32 u) { return __uint_as_float(u << 16); }
__device__ __forceinline__ float bfHi(uint32 u) { return __uint_as_float(u & 0xffff0000u); }

__global__ void count_kernel(const int* __restrict__ dst, int* __restrict__ cnt, int E) {
    int i = blockIdx.x * blockDim.x + threadIdx.x;
    if (i < E) atomicAdd(&cnt[dst[i]], 1);
}

// single-block exclusive scan of cnt -> roff; also emits dinv = rsqrt(cnt+1)
__global__ __launch_bounds__(1024) void scan_kernel(const int* __restrict__ cnt,
                                                    int* __restrict__ roff,
                                                    float* __restrict__ dinv, int n) {
    __shared__ int wsum[16];
    __shared__ int carry_s, total_s;
    int tid = threadIdx.x;
    int lane = tid & 63, w = tid >> 6;
    if (tid == 0) carry_s = 0;
    __syncthreads();
    for (int base = 0; base < n; base += 1024) {
        int i = base + tid;
        int v = (i < n) ? cnt[i] : 0;
        if (i < n) dinv[i] = rsqrtf((float)v + 1.0f);  // +1 self-loop
        int s = v;
#pragma unroll
        for (int d = 1; d < 64; d <<= 1) {
            int t = __shfl_up(s, d, 64);
            if (lane >= d) s += t;
        }
        if (lane == 63) wsum[w] = s;
        __syncthreads();
        if (w == 0) {
            int wv = (lane < 16) ? wsum[lane] : 0;
            int ss = wv;
#pragma unroll
            for (int d = 1; d < 16; d <<= 1) {
                int t = __shfl_up(ss, d, 64);
                if (lane >= d) ss += t;
            }
            if (lane < 16) wsum[lane] = ss - wv;   // exclusive wave offsets
            if (lane == 15) total_s = ss;          // chunk total
        }
        __syncthreads();
        int carry = carry_s;
        if (i < n) roff[i] = carry + wsum[w] + (s - v);
        __syncthreads();
        if (tid == 0) carry_s += total_s;
        __syncthreads();
    }
}

// emits interleaved (src, norm) pairs per edge slot
__global__ void scatter_kernel(const int* __restrict__ src, const int* __restrict__ dst,
                               const int* __restrict__ roff, int* __restrict__ cur,
                               const float* __restrict__ dinv,
                               int2* __restrict__ ese, int E) {
    int i = blockIdx.x * blockDim.x + threadIdx.x;
    if (i < E) {
        int d = dst[i], s = src[i];
        int p = roff[d] + atomicAdd(&cur[d], 1);
        ese[p] = make_int2(s, __float_as_int(dinv[s] * dinv[d]));
    }
}

// ---------------------------------------------------------------- fp32 GEMM
// C[M x 256] = A[M x K] * B[K x 256], row-major. Tile 128x128xBK8, 256 thr, 8x8/thr.
// K-loop needs ~130-160 live VGPRs (64 acc + 16 a/b + addressing + staged loads).
// VGPR-allocation history (rocprof VGPR_Count / WRITE_SIZE / dur evidence):
//   R2  no bound        -> 128 VGPR, no spill,   85 us  (154 TF = 98% fp32 roofline)
//   R4  (256) template  ->  92 VGPR, L2-resident spill, 223 us
//   R5  (256,4) cap 128 ->  64 VGPR, 2GB scratch->HBM,  731 us
//   R6  (256,2) min 2   ->  92 VGPR, L2-resident spill, 222 us
// Lesson: __launch_bounds__ 2nd arg only RAISES the occupancy target (min);
// the allocator still trims VGPRs chasing occupancy above it. The direct
// knob is amdgpu_waves_per_eu(min,max): pinning max=2 gives a 256-VGPR
// budget with no incentive to trim below the ~130-160 live ranges.
// OUT_MODE: 1 = fp32 bias+relu, 2 = raw bf16 (packed 2/uint)
template <int K, int OUT_MODE>
__device__ __forceinline__ void sgemm_body(const float* __restrict__ A,
                                           const float* __restrict__ B,
                                           const float* __restrict__ bias,
                                           float* __restrict__ C, int M) {
    __shared__ float As[8][128];
    __shared__ float Bs[8][128];
    int tid = threadIdx.x;
    int tx = tid & 15, ty = tid >> 4;
    int rowBase = blockIdx.x * 128;
    int colBase = blockIdx.y * 128;
    float acc[8][8] = {};
    int ar = rowBase + (tid >> 1);
    int ak = (tid & 1) * 4;
    int bk = tid >> 5;
    int bn = colBase + (tid & 31) * 4;

    for (int k0 = 0; k0 < K; k0 += 8) {
        float4 av = make_float4(0.f, 0.f, 0.f, 0.f);
        if (ar < M) av = *(const float4*)&A[(size_t)ar * K + k0 + ak];
        float4 bv = *(const float4*)&B[(size_t)(k0 + bk) * 256 + bn];
        __syncthreads();
        As[ak + 0][tid >> 1] = av.x;
        As[ak + 1][tid >> 1] = av.y;
        As[ak + 2][tid >> 1] = av.z;
        As[ak + 3][tid >> 1] = av.w;
        *(float4*)&Bs[bk][(tid & 31) * 4] = bv;
        __syncthreads();
#pragma unroll
        for (int kk = 0; kk < 8; ++kk) {
            float4 a0 = *(const float4*)&As[kk][ty * 8];
            float4 a1 = *(const float4*)&As[kk][ty * 8 + 4];
            float4 b0 = *(const float4*)&Bs[kk][tx * 8];
            float4 b1 = *(const float4*)&Bs[kk][tx * 8 + 4];
            float a[8] = {a0.x, a0.y, a0.z, a0.w, a1.x, a1.y, a1.z, a1.w};
            float b[8] = {b0.x, b0.y, b0.z, b0.w, b1.x, b1.y, b1.z, b1.w};
#pragma unroll
            for (int i = 0; i < 8; ++i)
#pragma unroll
                for (int j = 0; j < 8; ++j) acc[i][j] += a[i] * b[j];
        }
    }
    float bcol[8];
#pragma unroll
    for (int j = 0; j < 8; ++j) bcol[j] = (OUT_MODE == 1) ? bias[colBase + tx * 8 + j] : 0.f;
#pragma unroll
    for (int i = 0; i < 8; ++i) {
        int r = rowBase + ty * 8 + i;
        if (r < M) {
            if (OUT_MODE == 2) {
                uint32* Cb = (uint32*)C;  // bf16 pairs, row stride 128 uints
                uint4 pk;
                pk.x = f2bf(acc[i][0]) | (f2bf(acc[i][1]) << 16);
                pk.y = f2bf(acc[i][2]) | (f2bf(acc[i][3]) << 16);
                pk.z = f2bf(acc[i][4]) | (f2bf(acc[i][5]) << 16);
                pk.w = f2bf(acc[i][6]) | (f2bf(acc[i][7]) << 16);
                *(uint4*)&Cb[(size_t)r * 128 + (colBase >> 1) + tx * 4] = pk;
            } else {
                float o[8];
#pragma unroll
                for (int j = 0; j < 8; ++j)
                    o[j] = fmaxf(acc[i][j] + bcol[j], 0.f);
                *(float4*)&C[(size_t)r * 256 + colBase + tx * 8] =
                    make_float4(o[0], o[1], o[2], o[3]);
                *(float4*)&C[(size_t)r * 256 + colBase + tx * 8 + 4] =
                    make_float4(o[4], o[5], o[6], o[7]);
            }
        }
    }
}

__global__ __launch_bounds__(256)
__attribute__((amdgpu_waves_per_eu(2, 2)))
void sgemm1_kernel(const float* __restrict__ A, const float* __restrict__ B,
                   const float* __restrict__ bias, float* __restrict__ C, int M) {
    sgemm_body<128, 1>(A, B, bias, C, M);
}

__global__ __launch_bounds__(256)
__attribute__((amdgpu_waves_per_eu(2, 2)))
void sgemm2_kernel(const float* __restrict__ A, const float* __restrict__ B,
                   float* __restrict__ C, int M) {
    sgemm_body<256, 2>(A, B, nullptr, C, M);
}

// ------------------------------------------------------------- aggregation
// Layer 1: one wave per node, fp32 float2/lane over D=128 rows of x.
// Edge (src,norm) batches (64 int2) vector-loaded then readlane-broadcast;
// row gathers unrolled x8 for 8 loads in flight.
__global__ __launch_bounds__(256) void agg1_kernel(const float2* __restrict__ X,
                                                   const int* __restrict__ roff,
                                                   const int* __restrict__ cnt,
                                                   const int2* __restrict__ ese,
                                                   const float* __restrict__ dinv,
                                                   float2* __restrict__ out, int n) {
    int wv = threadIdx.x >> 6, lane = threadIdx.x & 63;
    int node = blockIdx.x * 4 + wv;
    if (node >= n) return;

    float di = dinv[node];
    float sn = di * di;  // self-loop norm
    float2 acc = X[(size_t)node * 64 + lane];
    acc.x *= sn; acc.y *= sn;

    int beg = roff[node], m = cnt[node];
    for (int base = 0; base < m; base += 64) {
        int mm = min(64, m - base);
        int2 ev = make_int2(0, 0);
        if (lane < mm) ev = ese[beg + base + lane];
        int e = 0;
        for (; e + 8 <= mm; e += 8) {
            int s0 = rl(ev.x, e + 0), s1 = rl(ev.x, e + 1);
            int s2 = rl(ev.x, e + 2), s3 = rl(ev.x, e + 3);
            int s4 = rl(ev.x, e + 4), s5 = rl(ev.x, e + 5);
            int s6 = rl(ev.x, e + 6), s7 = rl(ev.x, e + 7);
            float n0 = rlf(ev.y, e + 0), n1 = rlf(ev.y, e + 1);
            float n2 = rlf(ev.y, e + 2), n3 = rlf(ev.y, e + 3);
            float n4 = rlf(ev.y, e + 4), n5 = rlf(ev.y, e + 5);
            float n6 = rlf(ev.y, e + 6), n7 = rlf(ev.y, e + 7);
            float2 h0 = X[(size_t)s0 * 64 + lane];
            float2 h1 = X[(size_t)s1 * 64 + lane];
            float2 h2 = X[(size_t)s2 * 64 + lane];
            float2 h3 = X[(size_t)s3 * 64 + lane];
            float2 h4 = X[(size_t)s4 * 64 + lane];
            float2 h5 = X[(size_t)s5 * 64 + lane];
            float2 h6 = X[(size_t)s6 * 64 + lane];
            float2 h7 = X[(size_t)s7 * 64 + lane];
            acc.x += h0.x * n0 + h1.x * n1 + h2.x * n2 + h3.x * n3;
            acc.y += h0.y * n0 + h1.y * n1 + h2.y * n2 + h3.y * n3;
            acc.x += h4.x * n4 + h5.x * n5 + h6.x * n6 + h7.x * n7;
            acc.y += h4.y * n4 + h5.y * n5 + h6.y * n6 + h7.y * n7;
        }
        for (; e < mm; ++e) {
            int s0 = rl(ev.x, e);
            float n0 = rlf(ev.y, e);
            float2 h0 = X[(size_t)s0 * 64 + lane];
            acc.x += h0.x * n0;
            acc.y += h0.y * n0;
        }
    }
    out[(size_t)node * 64 + lane] = acc;
}

// Layer 2: 2 waves per node, bf16 payload (1 uint = 2 channels per lane),
// fp32 accumulate, fused bias + relu, fp32 output.
__global__ __launch_bounds__(256) void agg2_kernel(const uint32* __restrict__ Hbf,
                                                   const int* __restrict__ roff,
                                                   const int* __restrict__ cnt,
                                                   const int2* __restrict__ ese,
                                                   const float* __restrict__ dinv,
                                                   const float* __restrict__ bias,
                                                   float2* __restrict__ out, int n) {
    int wv = threadIdx.x >> 6, lane = threadIdx.x & 63;
    int gw = blockIdx.x * 4 + wv;
    int node = gw >> 1, half = gw & 1;
    if (node >= n) return;
    int offU = half * 64 + lane;  // uint offset within row (128 uints/row)

    float di = dinv[node];
    float sn = di * di;
    uint32 sg = Hbf[(size_t)node * 128 + offU];
    float2 acc;
    acc.x = bfLo(sg) * sn;
    acc.y = bfHi(sg) * sn;

    int beg = roff[node], m = cnt[node];
    for (int base = 0; base < m; base += 64) {
        int mm = min(64, m - base);
        int2 ev = make_int2(0, 0);
        if (lane < mm) ev = ese[beg + base + lane];
        int e = 0;
        for (; e + 8 <= mm; e += 8) {
            int s0 = rl(ev.x, e + 0), s1 = rl(ev.x, e + 1);
            int s2 = rl(ev.x, e + 2), s3 = rl(ev.x, e + 3);
            int s4 = rl(ev.x, e + 4), s5 = rl(ev.x, e + 5);
            int s6 = rl(ev.x, e + 6), s7 = rl(ev.x, e + 7);
            float n0 = rlf(ev.y, e + 0), n1 = rlf(ev.y, e + 1);
            float n2 = rlf(ev.y, e + 2), n3 = rlf(ev.y, e + 3);
            float n4 = rlf(ev.y, e + 4), n5 = rlf(ev.y, e + 5);
            float n6 = rlf(ev.y, e + 6), n7 = rlf(ev.y, e + 7);
            uint32 g0 = Hbf[(size_t)s0 * 128 + offU];
            uint32 g1 = Hbf[(size_t)s1 * 128 + offU];
            uint32 g2 = Hbf[(size_t)s2 * 128 + offU];
            uint32 g3 = Hbf[(size_t)s3 * 128 + offU];
            uint32 g4 = Hbf[(size_t)s4 * 128 + offU];
            uint32 g5 = Hbf[(size_t)s5 * 128 + offU];
            uint32 g6 = Hbf[(size_t)s6 * 128 + offU];
            uint32 g7 = Hbf[(size_t)s7 * 128 + offU];
            acc.x += bfLo(g0) * n0 + bfLo(g1) * n1 + bfLo(g2) * n2 + bfLo(g3) * n3;
            acc.y += bfHi(g0) * n0 + bfHi(g1) * n1 + bfHi(g2) * n2 + bfHi(g3) * n3;
            acc.x += bfLo(g4) * n4 + bfLo(g5) * n5 + bfLo(g6) * n6 + bfLo(g7) * n7;
            acc.y += bfHi(g4) * n4 + bfHi(g5) * n5 + bfHi(g6) * n6 + bfHi(g7) * n7;
        }
        for (; e < mm; ++e) {
            int s0 = rl(ev.x, e);
            float n0 = rlf(ev.y, e);
            uint32 g0 = Hbf[(size_t)s0 * 128 + offU];
            acc.x += bfLo(g0) * n0;
            acc.y += bfHi(g0) * n0;
        }
    }
    float2 bb = ((const float2*)bias)[offU];
    acc.x = fmaxf(acc.x + bb.x, 0.f);
    acc.y = fmaxf(acc.y + bb.y, 0.f);
    out[(size_t)node * 128 + offU] = acc;
}

// ---------------------------------------------------------------- launcher

extern "C" void kernel_launch(void* const* d_in, const int* in_sizes, int n_in,
                              void* d_out, int out_size, void* d_ws, size_t ws_size,
                              hipStream_t stream) {
    const float* x  = (const float*)d_in[0];
    const int*   ei = (const int*)d_in[1];
    const float* W1 = (const float*)d_in[2];
    const float* b1 = (const float*)d_in[3];
    const float* W2 = (const float*)d_in[4];
    const float* b2 = (const float*)d_in[5];
    float* out = (float*)d_out;

    const int n = in_sizes[0] / 128;   // 100000 nodes
    const int E = in_sizes[1] / 2;     // 1.6M edges
    const int* src = ei;
    const int* dst = ei + E;

    // workspace carve-up (256B aligned); cnt+cur adjacent -> one memset
    size_t off = 0;
    auto alloc = [&](size_t bytes) {
        void* p = (char*)d_ws + off;
        off += (bytes + 255) & ~(size_t)255;
        return p;
    };
    int*   cnt  = (int*)alloc((size_t)n * 4);
    int*   cur  = (int*)alloc((size_t)n * 4);
    int*   roff = (int*)alloc((size_t)n * 4);
    float* dinv = (float*)alloc((size_t)n * 4);
    int2*  ese  = (int2*)alloc((size_t)E * 8);
    // shared buffer: agg1 output (n x 128 fp32 = 51.2MB), then h2-bf16 (n x 256 bf16 = 51.2MB)
    float* buf  = (float*)alloc((size_t)n * 128 * 4);
    (void)ws_size;

    // ---- graph build
    hipMemsetAsync(cnt, 0, (size_t)(2 * n + 128) * 4, stream);  // cnt + cur (adjacent)
    count_kernel<<<(E + 255) / 256, 256, 0, stream>>>(dst, cnt, E);
    scan_kernel<<<1, 1024, 0, stream>>>(cnt, roff, dinv, n);
    scatter_kernel<<<(E + 255) / 256, 256, 0, stream>>>(src, dst, roff, cur, dinv, ese, E);

    dim3 g1((n + 127) / 128, 2);
    // ---- layer 1: ax = Âx (128-dim); out = relu(ax @ W1 + b1)
    agg1_kernel<<<(n + 3) / 4, 256, 0, stream>>>(
        (const float2*)x, roff, cnt, ese, dinv, (float2*)buf, n);
    sgemm1_kernel<<<g1, 256, 0, stream>>>(buf, W1, b1, out, n);

    // ---- layer 2: h2 = bf16(out @ W2) ; out = relu(Â h2 + b2)
    sgemm2_kernel<<<g1, 256, 0, stream>>>(out, W2, buf, n);
    agg2_kernel<<<(2 * n + 3) / 4, 256, 0, stream>>>(
        (const uint32*)buf, roff, cnt, ese, dinv, b2, (float2*)out, n);
}

// Round 9
// 899.352 us; speedup vs baseline: 1.5741x; 1.0381x over previous
//
#include <hip/hip_runtime.h>

typedef unsigned int uint32;

// ---------------------------------------------------------------- utilities

__device__ __forceinline__ int rl(int v, int l) {
    return __builtin_amdgcn_readlane(v, l);
}
__device__ __forceinline__ float rlf(int v, int l) {
    return __int_as_float(__builtin_amdgcn_readlane(v, l));
}
__device__ __forceinline__ uint32 f2bf(float x) {  // RNE f32 -> bf16 (low 16 bits)
    uint32 u = __float_as_uint(x);
    return (u + 0x7fffu + ((u >> 16) & 1u)) >> 16;
}
__device__ __forceinline__ float bfLo(uint32 u) { return __uint_as_float(u << 16); }
__device__ __forceinline__ float bfHi(uint32 u) { return __uint_as_float(u & 0xffff0000u); }

__global__ void count_kernel(const int* __restrict__ dst, int* __restrict__ cnt, int E) {
    int i = blockIdx.x * blockDim.x + threadIdx.x;
    if (i < E) atomicAdd(&cnt[dst[i]], 1);
}

// single-block exclusive scan of cnt -> roff; also emits dinv = rsqrt(cnt+1)
__global__ __launch_bounds__(1024) void scan_kernel(const int* __restrict__ cnt,
                                                    int* __restrict__ roff,
                                                    float* __restrict__ dinv, int n) {
    __shared__ int wsum[16];
    __shared__ int carry_s, total_s;
    int tid = threadIdx.x;
    int lane = tid & 63, w = tid >> 6;
    if (tid == 0) carry_s = 0;
    __syncthreads();
    for (int base = 0; base < n; base += 1024) {
        int i = base + tid;
        int v = (i < n) ? cnt[i] : 0;
        if (i < n) dinv[i] = rsqrtf((float)v + 1.0f);  // +1 self-loop
        int s = v;
#pragma unroll
        for (int d = 1; d < 64; d <<= 1) {
            int t = __shfl_up(s, d, 64);
            if (lane >= d) s += t;
        }
        if (lane == 63) wsum[w] = s;
        __syncthreads();
        if (w == 0) {
            int wv = (lane < 16) ? wsum[lane] : 0;
            int ss = wv;
#pragma unroll
            for (int d = 1; d < 16; d <<= 1) {
                int t = __shfl_up(ss, d, 64);
                if (lane >= d) ss += t;
            }
            if (lane < 16) wsum[lane] = ss - wv;   // exclusive wave offsets
            if (lane == 15) total_s = ss;          // chunk total
        }
        __syncthreads();
        int carry = carry_s;
        if (i < n) roff[i] = carry + wsum[w] + (s - v);
        __syncthreads();
        if (tid == 0) carry_s += total_s;
        __syncthreads();
    }
}

// emits interleaved (src, norm) pairs per edge slot
__global__ void scatter_kernel(const int* __restrict__ src, const int* __restrict__ dst,
                               const int* __restrict__ roff, int* __restrict__ cur,
                               const float* __restrict__ dinv,
                               int2* __restrict__ ese, int E) {
    int i = blockIdx.x * blockDim.x + threadIdx.x;
    if (i < E) {
        int d = dst[i], s = src[i];
        int p = roff[d] + atomicAdd(&cur[d], 1);
        ese[p] = make_int2(s, __float_as_int(dinv[s] * dinv[d]));
    }
}

// ---------------------------------------------------------------- fp32 GEMM
// C[M x 256] = A[M x K] * B[K x 256], row-major.
// Tile 64x128xBK8, 256 thr, 4x8 acc/thread (~32 acc + ~25 misc live VGPRs).
// REDESIGN RATIONALE (R4-R7 evidence): the old 128x128 / 8x8-acc kernel needs
// ~130-160 live VGPRs; hipcc's allocator insisted on 92-96 VGPRs regardless of
// __launch_bounds__(256,4)/(256,2)/waves_per_eu(2,2) (three failed rounds:
// VGPR_Count 92/64/96, dur 222-731 us vs R2's accidental 128-VGPR 85 us build).
// Instead of fighting the heuristic, this shape FITS the 92-96 budget by
// construction. Per-thread cols split {tx*4, 64+tx*4} -> 4-float lane stride
// -> 2-way LDS bank aliasing (free) vs old tx*8 stride (4-way conflict,
// SQ_LDS_BANK_CONFLICT=1.44e7). 2x blocks also raises resident waves.
// OUT_MODE: 1 = fp32 bias+relu, 2 = raw bf16 (packed 2/uint)
template <int K, int OUT_MODE>
__device__ __forceinline__ void sgemm_body(const float* __restrict__ A,
                                           const float* __restrict__ B,
                                           const float* __restrict__ bias,
                                           float* __restrict__ C, int M) {
    __shared__ float As[8][64];
    __shared__ float Bs[8][128];
    int tid = threadIdx.x;
    int tx = tid & 15;        // col group 0-15
    int ty = tid >> 4;        // row group 0-15
    int rowBase = blockIdx.x * 64;
    int colBase = blockIdx.y * 128;
    float acc[4][8] = {};
    int ar = tid >> 2;        // staging row 0-63
    int ak = (tid & 3) * 2;   // staging k offset 0,2,4,6
    int bk = tid >> 5;        // staging k 0-7
    int bn = (tid & 31) * 4;  // staging col

    for (int k0 = 0; k0 < K; k0 += 8) {
        float2 av = make_float2(0.f, 0.f);
        int arow = rowBase + ar;
        if (arow < M) av = *(const float2*)&A[(size_t)arow * K + k0 + ak];
        float4 bv = *(const float4*)&B[(size_t)(k0 + bk) * 256 + colBase + bn];
        __syncthreads();
        As[ak + 0][ar] = av.x;
        As[ak + 1][ar] = av.y;
        *(float4*)&Bs[bk][bn] = bv;
        __syncthreads();
#pragma unroll
        for (int kk = 0; kk < 8; ++kk) {
            float4 a0 = *(const float4*)&As[kk][ty * 4];
            float4 b0 = *(const float4*)&Bs[kk][tx * 4];
            float4 b1 = *(const float4*)&Bs[kk][64 + tx * 4];
            float a[4] = {a0.x, a0.y, a0.z, a0.w};
            float b[8] = {b0.x, b0.y, b0.z, b0.w, b1.x, b1.y, b1.z, b1.w};
#pragma unroll
            for (int i = 0; i < 4; ++i)
#pragma unroll
                for (int j = 0; j < 8; ++j) acc[i][j] += a[i] * b[j];
        }
    }
    int c0 = colBase + tx * 4;       // first 4-col group
    int c1 = colBase + 64 + tx * 4;  // second 4-col group
    float bcol[8];
    if (OUT_MODE == 1) {
#pragma unroll
        for (int j = 0; j < 4; ++j) { bcol[j] = bias[c0 + j]; bcol[4 + j] = bias[c1 + j]; }
    }
#pragma unroll
    for (int i = 0; i < 4; ++i) {
        int r = rowBase + ty * 4 + i;
        if (r < M) {
            if (OUT_MODE == 2) {
                uint32* Cb = (uint32*)C;  // bf16 pairs, row stride 128 uints
                uint2 p0, p1;
                p0.x = f2bf(acc[i][0]) | (f2bf(acc[i][1]) << 16);
                p0.y = f2bf(acc[i][2]) | (f2bf(acc[i][3]) << 16);
                p1.x = f2bf(acc[i][4]) | (f2bf(acc[i][5]) << 16);
                p1.y = f2bf(acc[i][6]) | (f2bf(acc[i][7]) << 16);
                *(uint2*)&Cb[(size_t)r * 128 + (c0 >> 1)] = p0;
                *(uint2*)&Cb[(size_t)r * 128 + (c1 >> 1)] = p1;
            } else {
                float4 o0, o1;
                o0.x = fmaxf(acc[i][0] + bcol[0], 0.f);
                o0.y = fmaxf(acc[i][1] + bcol[1], 0.f);
                o0.z = fmaxf(acc[i][2] + bcol[2], 0.f);
                o0.w = fmaxf(acc[i][3] + bcol[3], 0.f);
                o1.x = fmaxf(acc[i][4] + bcol[4], 0.f);
                o1.y = fmaxf(acc[i][5] + bcol[5], 0.f);
                o1.z = fmaxf(acc[i][6] + bcol[6], 0.f);
                o1.w = fmaxf(acc[i][7] + bcol[7], 0.f);
                *(float4*)&C[(size_t)r * 256 + c0] = o0;
                *(float4*)&C[(size_t)r * 256 + c1] = o1;
            }
        }
    }
}

__global__ __launch_bounds__(256) void sgemm1_kernel(const float* __restrict__ A,
                                                     const float* __restrict__ B,
                                                     const float* __restrict__ bias,
                                                     float* __restrict__ C, int M) {
    sgemm_body<128, 1>(A, B, bias, C, M);
}

__global__ __launch_bounds__(256) void sgemm2_kernel(const float* __restrict__ A,
                                                     const float* __restrict__ B,
                                                     float* __restrict__ C, int M) {
    sgemm_body<256, 2>(A, B, nullptr, C, M);
}

// ------------------------------------------------------------- aggregation
// Layer 1: one wave per node, fp32 float2/lane over D=128 rows of x.
// Edge (src,norm) batches (64 int2) vector-loaded then readlane-broadcast;
// row gathers unrolled x8 for 8 loads in flight.
__global__ __launch_bounds__(256) void agg1_kernel(const float2* __restrict__ X,
                                                   const int* __restrict__ roff,
                                                   const int* __restrict__ cnt,
                                                   const int2* __restrict__ ese,
                                                   const float* __restrict__ dinv,
                                                   float2* __restrict__ out, int n) {
    int wv = threadIdx.x >> 6, lane = threadIdx.x & 63;
    int node = blockIdx.x * 4 + wv;
    if (node >= n) return;

    float di = dinv[node];
    float sn = di * di;  // self-loop norm
    float2 acc = X[(size_t)node * 64 + lane];
    acc.x *= sn; acc.y *= sn;

    int beg = roff[node], m = cnt[node];
    for (int base = 0; base < m; base += 64) {
        int mm = min(64, m - base);
        int2 ev = make_int2(0, 0);
        if (lane < mm) ev = ese[beg + base + lane];
        int e = 0;
        for (; e + 8 <= mm; e += 8) {
            int s0 = rl(ev.x, e + 0), s1 = rl(ev.x, e + 1);
            int s2 = rl(ev.x, e + 2), s3 = rl(ev.x, e + 3);
            int s4 = rl(ev.x, e + 4), s5 = rl(ev.x, e + 5);
            int s6 = rl(ev.x, e + 6), s7 = rl(ev.x, e + 7);
            float n0 = rlf(ev.y, e + 0), n1 = rlf(ev.y, e + 1);
            float n2 = rlf(ev.y, e + 2), n3 = rlf(ev.y, e + 3);
            float n4 = rlf(ev.y, e + 4), n5 = rlf(ev.y, e + 5);
            float n6 = rlf(ev.y, e + 6), n7 = rlf(ev.y, e + 7);
            float2 h0 = X[(size_t)s0 * 64 + lane];
            float2 h1 = X[(size_t)s1 * 64 + lane];
            float2 h2 = X[(size_t)s2 * 64 + lane];
            float2 h3 = X[(size_t)s3 * 64 + lane];
            float2 h4 = X[(size_t)s4 * 64 + lane];
            float2 h5 = X[(size_t)s5 * 64 + lane];
            float2 h6 = X[(size_t)s6 * 64 + lane];
            float2 h7 = X[(size_t)s7 * 64 + lane];
            acc.x += h0.x * n0 + h1.x * n1 + h2.x * n2 + h3.x * n3;
            acc.y += h0.y * n0 + h1.y * n1 + h2.y * n2 + h3.y * n3;
            acc.x += h4.x * n4 + h5.x * n5 + h6.x * n6 + h7.x * n7;
            acc.y += h4.y * n4 + h5.y * n5 + h6.y * n6 + h7.y * n7;
        }
        for (; e < mm; ++e) {
            int s0 = rl(ev.x, e);
            float n0 = rlf(ev.y, e);
            float2 h0 = X[(size_t)s0 * 64 + lane];
            acc.x += h0.x * n0;
            acc.y += h0.y * n0;
        }
    }
    out[(size_t)node * 64 + lane] = acc;
}

// Layer 2: 2 waves per node, bf16 payload (1 uint = 2 channels per lane),
// fp32 accumulate, fused bias + relu, fp32 output.
__global__ __launch_bounds__(256) void agg2_kernel(const uint32* __restrict__ Hbf,
                                                   const int* __restrict__ roff,
                                                   const int* __restrict__ cnt,
                                                   const int2* __restrict__ ese,
                                                   const float* __restrict__ dinv,
                                                   const float* __restrict__ bias,
                                                   float2* __restrict__ out, int n) {
    int wv = threadIdx.x >> 6, lane = threadIdx.x & 63;
    int gw = blockIdx.x * 4 + wv;
    int node = gw >> 1, half = gw & 1;
    if (node >= n) return;
    int offU = half * 64 + lane;  // uint offset within row (128 uints/row)

    float di = dinv[node];
    float sn = di * di;
    uint32 sg = Hbf[(size_t)node * 128 + offU];
    float2 acc;
    acc.x = bfLo(sg) * sn;
    acc.y = bfHi(sg) * sn;

    int beg = roff[node], m = cnt[node];
    for (int base = 0; base < m; base += 64) {
        int mm = min(64, m - base);
        int2 ev = make_int2(0, 0);
        if (lane < mm) ev = ese[beg + base + lane];
        int e = 0;
        for (; e + 8 <= mm; e += 8) {
            int s0 = rl(ev.x, e + 0), s1 = rl(ev.x, e + 1);
            int s2 = rl(ev.x, e + 2), s3 = rl(ev.x, e + 3);
            int s4 = rl(ev.x, e + 4), s5 = rl(ev.x, e + 5);
            int s6 = rl(ev.x, e + 6), s7 = rl(ev.x, e + 7);
            float n0 = rlf(ev.y, e + 0), n1 = rlf(ev.y, e + 1);
            float n2 = rlf(ev.y, e + 2), n3 = rlf(ev.y, e + 3);
            float n4 = rlf(ev.y, e + 4), n5 = rlf(ev.y, e + 5);
            float n6 = rlf(ev.y, e + 6), n7 = rlf(ev.y, e + 7);
            uint32 g0 = Hbf[(size_t)s0 * 128 + offU];
            uint32 g1 = Hbf[(size_t)s1 * 128 + offU];
            uint32 g2 = Hbf[(size_t)s2 * 128 + offU];
            uint32 g3 = Hbf[(size_t)s3 * 128 + offU];
            uint32 g4 = Hbf[(size_t)s4 * 128 + offU];
            uint32 g5 = Hbf[(size_t)s5 * 128 + offU];
            uint32 g6 = Hbf[(size_t)s6 * 128 + offU];
            uint32 g7 = Hbf[(size_t)s7 * 128 + offU];
            acc.x += bfLo(g0) * n0 + bfLo(g1) * n1 + bfLo(g2) * n2 + bfLo(g3) * n3;
            acc.y += bfHi(g0) * n0 + bfHi(g1) * n1 + bfHi(g2) * n2 + bfHi(g3) * n3;
            acc.x += bfLo(g4) * n4 + bfLo(g5) * n5 + bfLo(g6) * n6 + bfLo(g7) * n7;
            acc.y += bfHi(g4) * n4 + bfHi(g5) * n5 + bfHi(g6) * n6 + bfHi(g7) * n7;
        }
        for (; e < mm; ++e) {
            int s0 = rl(ev.x, e);
            float n0 = rlf(ev.y, e);
            uint32 g0 = Hbf[(size_t)s0 * 128 + offU];
            acc.x += bfLo(g0) * n0;
            acc.y += bfHi(g0) * n0;
        }
    }
    float2 bb = ((const float2*)bias)[offU];
    acc.x = fmaxf(acc.x + bb.x, 0.f);
    acc.y = fmaxf(acc.y + bb.y, 0.f);
    out[(size_t)node * 128 + offU] = acc;
}

// ---------------------------------------------------------------- launcher

extern "C" void kernel_launch(void* const* d_in, const int* in_sizes, int n_in,
                              void* d_out, int out_size, void* d_ws, size_t ws_size,
                              hipStream_t stream) {
    const float* x  = (const float*)d_in[0];
    const int*   ei = (const int*)d_in[1];
    const float* W1 = (const float*)d_in[2];
    const float* b1 = (const float*)d_in[3];
    const float* W2 = (const float*)d_in[4];
    const float* b2 = (const float*)d_in[5];
    float* out = (float*)d_out;

    const int n = in_sizes[0] / 128;   // 100000 nodes
    const int E = in_sizes[1] / 2;     // 1.6M edges
    const int* src = ei;
    const int* dst = ei + E;

    // workspace carve-up (256B aligned); cnt+cur adjacent -> one memset
    size_t off = 0;
    auto alloc = [&](size_t bytes) {
        void* p = (char*)d_ws + off;
        off += (bytes + 255) & ~(size_t)255;
        return p;
    };
    int*   cnt  = (int*)alloc((size_t)n * 4);
    int*   cur  = (int*)alloc((size_t)n * 4);
    int*   roff = (int*)alloc((size_t)n * 4);
    float* dinv = (float*)alloc((size_t)n * 4);
    int2*  ese  = (int2*)alloc((size_t)E * 8);
    // shared buffer: agg1 output (n x 128 fp32 = 51.2MB), then h2-bf16 (n x 256 bf16 = 51.2MB)
    float* buf  = (float*)alloc((size_t)n * 128 * 4);
    (void)ws_size;

    // ---- graph build
    hipMemsetAsync(cnt, 0, (size_t)(2 * n + 128) * 4, stream);  // cnt + cur (adjacent)
    count_kernel<<<(E + 255) / 256, 256, 0, stream>>>(dst, cnt, E);
    scan_kernel<<<1, 1024, 0, stream>>>(cnt, roff, dinv, n);
    scatter_kernel<<<(E + 255) / 256, 256, 0, stream>>>(src, dst, roff, cur, dinv, ese, E);

    dim3 g1((n + 63) / 64, 2);
    // ---- layer 1: ax = Âx (128-dim); out = relu(ax @ W1 + b1)
    agg1_kernel<<<(n + 3) / 4, 256, 0, stream>>>(
        (const float2*)x, roff, cnt, ese, dinv, (float2*)buf, n);
    sgemm1_kernel<<<g1, 256, 0, stream>>>(buf, W1, b1, out, n);

    // ---- layer 2: h2 = bf16(out @ W2) ; out = relu(Â h2 + b2)
    sgemm2_kernel<<<g1, 256, 0, stream>>>(out, W2, buf, n);
    agg2_kernel<<<(2 * n + 3) / 4, 256, 0, stream>>>(
        (const uint32*)buf, roff, cnt, ese, dinv, b2, (float2*)out, n);
}